// Round 1
// baseline (913.341 us; speedup 1.0000x reference)
//
#include <hip/hip_runtime.h>
#include <math.h>

// Problem constants (from reference)
#define NNODE  100000
#define NEDGE  3200000
#define DFEAT  256
#define NCLS   40
#define NC_TOT 4000000        // NNODE * NCLS
#define NIDS   1000
#define TOLSQ  1.0e-4f        // TOL^2, TOL = 0.01
#define MAXIT  16

#define VB 1024               // blocks for vector-length kernels
#define VT 256
#define SCAN_T 1024
#define SCAN_B 98             // ceil(NNODE / SCAN_T)
#define GEMM_ROWS 256
#define GEMM_KC   32
#define GEMM_B    391         // ceil(NNODE / GEMM_ROWS)

__device__ __forceinline__ float block_reduce_256(float v, float* red) {
  int tid = threadIdx.x;
  red[tid] = v;
  __syncthreads();
  #pragma unroll
  for (int off = 128; off > 0; off >>= 1) {
    if (tid < off) red[tid] += red[tid + off];
    __syncthreads();
  }
  float res = red[0];
  __syncthreads();
  return res;
}

// ------------------- CSR build -------------------
__global__ void k_hist(const int* __restrict__ row, int* __restrict__ cnt) {
  int stride = gridDim.x * blockDim.x;
  for (int i = blockIdx.x * blockDim.x + threadIdx.x; i < NEDGE; i += stride)
    atomicAdd(&cnt[row[i]], 1);
}

__global__ void k_scan_a(int* __restrict__ data, int* __restrict__ blocksums) {
  __shared__ int s[SCAN_T];
  int tid = threadIdx.x;
  int i = blockIdx.x * SCAN_T + tid;
  int v = (i < NNODE) ? data[i] : 0;
  s[tid] = v;
  __syncthreads();
  for (int off = 1; off < SCAN_T; off <<= 1) {
    int t = (tid >= off) ? s[tid - off] : 0;
    __syncthreads();
    s[tid] += t;
    __syncthreads();
  }
  if (i < NNODE) data[i] = s[tid] - v;             // exclusive within chunk
  if (tid == SCAN_T - 1) blocksums[blockIdx.x] = s[tid];
}

__global__ void k_scan_b(int* __restrict__ blocksums) {
  __shared__ int s[128];
  int tid = threadIdx.x;
  int v = (tid < SCAN_B) ? blocksums[tid] : 0;
  s[tid] = v;
  __syncthreads();
  for (int off = 1; off < 128; off <<= 1) {
    int t = (tid >= off) ? s[tid - off] : 0;
    __syncthreads();
    s[tid] += t;
    __syncthreads();
  }
  if (tid < SCAN_B) blocksums[tid] = s[tid] - v;   // exclusive
}

__global__ void k_scan_c(int* __restrict__ rowptr, const int* __restrict__ blocksums,
                         int* __restrict__ cursor) {
  int i = blockIdx.x * blockDim.x + threadIdx.x;
  if (i < NNODE) {
    int v = rowptr[i] + blocksums[i / SCAN_T];
    rowptr[i] = v;
    cursor[i] = v;
  }
  if (i == 0) rowptr[NNODE] = NEDGE;
}

__global__ void k_scatter(const int* __restrict__ row, const int* __restrict__ col,
                          const float* __restrict__ data, int* __restrict__ cursor,
                          int2* __restrict__ csr) {
  int stride = gridDim.x * blockDim.x;
  for (int i = blockIdx.x * blockDim.x + threadIdx.x; i < NEDGE; i += stride) {
    int rr = row[i];
    int pos = atomicAdd(&cursor[rr], 1);
    csr[pos] = make_int2(col[i], __float_as_int(data[i]));
  }
}

// ------------------- init: b_vec = X@W + b; x=0; r=p=b_vec; <b,b> partials ---
__global__ void __launch_bounds__(256) k_gemm(const float* __restrict__ feat,
    const float* __restrict__ W, const float* __restrict__ bias,
    float* __restrict__ x, float* __restrict__ r, float* __restrict__ p,
    float* __restrict__ part) {
  __shared__ float ftile[GEMM_ROWS][GEMM_KC + 1];
  __shared__ float red[256];
  int tid = threadIdx.x;
  int r0 = blockIdx.x * GEMM_ROWS;
  float acc[NCLS];
  #pragma unroll
  for (int c = 0; c < NCLS; ++c) acc[c] = bias[c];

  for (int k0 = 0; k0 < DFEAT; k0 += GEMM_KC) {
    __syncthreads();
    #pragma unroll
    for (int it = 0; it < (GEMM_ROWS * GEMM_KC / 4) / 256; ++it) {
      int i = tid + it * 256;
      int rr = i >> 3, kq = i & 7;
      int grow = r0 + rr;
      float4 v = make_float4(0.f, 0.f, 0.f, 0.f);
      if (grow < NNODE)
        v = *(const float4*)(feat + (size_t)grow * DFEAT + k0 + kq * 4);
      ftile[rr][kq * 4 + 0] = v.x;
      ftile[rr][kq * 4 + 1] = v.y;
      ftile[rr][kq * 4 + 2] = v.z;
      ftile[rr][kq * 4 + 3] = v.w;
    }
    __syncthreads();
    #pragma unroll 2
    for (int kk = 0; kk < GEMM_KC; ++kk) {
      float f = ftile[tid][kk];
      const float* wrow = W + (k0 + kk) * NCLS;   // uniform -> scalar loads
      #pragma unroll
      for (int c = 0; c < NCLS; ++c) acc[c] = fmaf(f, wrow[c], acc[c]);
    }
  }

  int grow = r0 + tid;
  float local = 0.f;
  if (grow < NNODE) {
    size_t base = (size_t)grow * NCLS;
    #pragma unroll
    for (int c = 0; c < NCLS; ++c) {
      float a = acc[c];
      r[base + c] = a;
      p[base + c] = a;
      x[base + c] = 0.f;
      local = fmaf(a, a, local);
    }
  }
  float tot = block_reduce_256(local, red);
  if (tid == 0) part[blockIdx.x] = tot;
}

// scalars: scal[0]=omega(=1-eps), scal[1]=atol2, scal[2+k]=gamma_k
__global__ void k_init_scal(const float* __restrict__ part, const float* __restrict__ e0,
                            float* __restrict__ scal) {
  __shared__ float red[256];
  float local = 0.f;
  for (int i = threadIdx.x; i < GEMM_B; i += 256) local += part[i];
  float bs = block_reduce_256(local, red);
  if (threadIdx.x == 0) {
    float eps = 1.f / (1.f + expf(-e0[0]));
    scal[0] = 1.f - eps;
    scal[1] = TOLSQ * bs;
    scal[2] = bs;          // gamma_0 = <r0,r0> = <b,b>
  }
}

// ------------------- CG iteration kernels (device-side convergence guard) ---
__global__ void __launch_bounds__(VT) k_spmv(const float* __restrict__ scal, int k,
    const int* __restrict__ rowptr, const int2* __restrict__ csr,
    const float* __restrict__ p, float* __restrict__ Ap, float* __restrict__ part) {
  float gamma = scal[2 + k], atol2 = scal[1];
  if (!(gamma > atol2)) return;               // mirrors JAX while cond (rs > atol2)
  float omega = scal[0];
  float local = 0.f;
  int stride = gridDim.x * blockDim.x;
  for (int e = blockIdx.x * blockDim.x + threadIdx.x; e < NC_TOT; e += stride) {
    int rr = e / NCLS;
    int c = e - rr * NCLS;
    int s0 = rowptr[rr], s1 = rowptr[rr + 1];
    float acc = 0.f;
    #pragma unroll 4
    for (int j = s0; j < s1; ++j) {
      int2 pr = csr[j];
      acc = fmaf(__int_as_float(pr.y), p[pr.x * NCLS + c], acc);
    }
    float pe = p[e];
    float v = fmaf(-omega, acc, pe);          // f(p) = p - (1-eps) * A p
    Ap[e] = v;
    local = fmaf(pe, v, local);               // <p, Ap> partial
  }
  __shared__ float red[256];
  float tot = block_reduce_256(local, red);
  if (threadIdx.x == 0) part[blockIdx.x] = tot;
}

__global__ void __launch_bounds__(VT) k_xr(const float* __restrict__ scal, int k,
    const float* __restrict__ part_in,
    const float* __restrict__ p, const float* __restrict__ Ap,
    float* __restrict__ x, float* __restrict__ r, float* __restrict__ part_out) {
  float gamma = scal[2 + k], atol2 = scal[1];
  if (!(gamma > atol2)) return;
  __shared__ float red[256];
  float lp = 0.f;
  for (int i = threadIdx.x; i < VB; i += VT) lp += part_in[i];
  float pap = block_reduce_256(lp, red);      // identical in every block
  float alpha = gamma / pap;
  float local = 0.f;
  int stride = gridDim.x * blockDim.x;
  for (int e = blockIdx.x * blockDim.x + threadIdx.x; e < NC_TOT; e += stride) {
    x[e] = fmaf(alpha, p[e], x[e]);
    float rn = fmaf(-alpha, Ap[e], r[e]);
    r[e] = rn;
    local = fmaf(rn, rn, local);              // <r',r'> partial
  }
  float tot = block_reduce_256(local, red);
  if (threadIdx.x == 0) part_out[blockIdx.x] = tot;
}

__global__ void __launch_bounds__(VT) k_pupd(float* __restrict__ scal, int k,
    const float* __restrict__ part_in,
    const float* __restrict__ r, float* __restrict__ p) {
  float gamma = scal[2 + k], atol2 = scal[1];
  if (!(gamma > atol2)) {
    if (blockIdx.x == 0 && threadIdx.x == 0) scal[2 + k + 1] = gamma;  // propagate
    return;
  }
  __shared__ float red[256];
  float lp = 0.f;
  for (int i = threadIdx.x; i < VB; i += VT) lp += part_in[i];
  float gnew = block_reduce_256(lp, red);
  float beta = gnew / gamma;
  int stride = gridDim.x * blockDim.x;
  for (int e = blockIdx.x * blockDim.x + threadIdx.x; e < NC_TOT; e += stride)
    p[e] = fmaf(beta, p[e], r[e]);
  if (blockIdx.x == 0 && threadIdx.x == 0) scal[2 + k + 1] = gnew;
}

__global__ void k_out(const float* __restrict__ x, const int* __restrict__ ids,
                      float* __restrict__ out) {
  int j = blockIdx.x * blockDim.x + threadIdx.x;
  if (j < NIDS * NCLS) {
    int i = j / NCLS, c = j - (j / NCLS) * NCLS;
    out[j] = x[(size_t)ids[i] * NCLS + c];
  }
}

// ------------------- host launch -------------------
extern "C" void kernel_launch(void* const* d_in, const int* in_sizes, int n_in,
                              void* d_out, int out_size, void* d_ws, size_t ws_size,
                              hipStream_t stream) {
  const float* feat = (const float*)d_in[0];
  const float* W    = (const float*)d_in[1];
  const float* bias = (const float*)d_in[2];
  const float* e0   = (const float*)d_in[3];
  const float* data = (const float*)d_in[4];
  const int*   row  = (const int*)d_in[5];
  const int*   col  = (const int*)d_in[6];
  const int*   ids  = (const int*)d_in[7];
  float* out = (float*)d_out;

  size_t off = 0;
  char* base = (char*)d_ws;
  auto take = [&](size_t nbytes) -> void* {
    void* ptr = base + off;
    off += (nbytes + 255) & ~(size_t)255;
    return ptr;
  };
  float* x   = (float*)take((size_t)NC_TOT * 4);
  float* rv  = (float*)take((size_t)NC_TOT * 4);
  float* pv  = (float*)take((size_t)NC_TOT * 4);
  float* ap  = (float*)take((size_t)NC_TOT * 4);
  int2*  csr = (int2*)take((size_t)NEDGE * 8);
  int* rowptr    = (int*)take((size_t)(NNODE + 1) * 4);
  int* cursor    = (int*)take((size_t)NNODE * 4);
  int* blocksums = (int*)take(128 * 4);
  float* part_a  = (float*)take(VB * 4);
  float* part_b  = (float*)take(VB * 4);
  float* scal    = (float*)take(64 * 4);

  // CSR build (counts live in rowptr[0..N))
  hipMemsetAsync(rowptr, 0, (size_t)(NNODE + 1) * 4, stream);
  k_hist<<<2048, 256, 0, stream>>>(row, rowptr);
  k_scan_a<<<SCAN_B, SCAN_T, 0, stream>>>(rowptr, blocksums);
  k_scan_b<<<1, 128, 0, stream>>>(blocksums);
  k_scan_c<<<(NNODE + 255) / 256, 256, 0, stream>>>(rowptr, blocksums, cursor);
  k_scatter<<<2048, 256, 0, stream>>>(row, col, data, cursor, csr);

  // init: b_vec, x0=0, r0=p0=b_vec, gamma0=<b,b>
  k_gemm<<<GEMM_B, 256, 0, stream>>>(feat, W, bias, x, rv, pv, part_a);
  k_init_scal<<<1, 256, 0, stream>>>(part_a, e0, scal);

  // 16 unrolled, device-guarded CG iterations
  for (int k = 0; k < MAXIT; ++k) {
    k_spmv<<<VB, VT, 0, stream>>>(scal, k, rowptr, csr, pv, ap, part_a);
    k_xr  <<<VB, VT, 0, stream>>>(scal, k, part_a, pv, ap, x, rv, part_b);
    k_pupd<<<VB, VT, 0, stream>>>(scal, k, part_b, rv, pv);
  }

  k_out<<<(NIDS * NCLS + 255) / 256, 256, 0, stream>>>(x, ids, out);
}

// Round 2
// 735.101 us; speedup vs baseline: 1.2425x; 1.2425x over previous
//
#include <hip/hip_runtime.h>
#include <math.h>

// Problem constants (from reference)
#define NNODE  100000
#define NEDGE  3200000
#define DFEAT  256
#define NCLS   40
#define NC_TOT 4000000        // NNODE * NCLS
#define NIDS   1000
#define TOLSQ  1.0e-4f        // TOL^2, TOL = 0.01
#define MAXIT  16

#define VB 1024               // blocks for vector-length kernels
#define VT 256
#define GEMM_ROWS 256
#define GEMM_KC   32
#define GEMM_B    391         // ceil(NNODE / GEMM_ROWS)

// Bucketed CSR build
#define RB      128           // rows per bucket (row >> 7)
#define NBUCK   782           // ceil(NNODE / RB)
#define BCAP    6144          // LDS edge capacity per bucket (mean 4096, sigma 64)

__device__ __forceinline__ float block_reduce_256(float v, float* red) {
  int tid = threadIdx.x;
  red[tid] = v;
  __syncthreads();
  #pragma unroll
  for (int off = 128; off > 0; off >>= 1) {
    if (tid < off) red[tid] += red[tid + off];
    __syncthreads();
  }
  float res = red[0];
  __syncthreads();
  return res;
}

// ------------------- bucketed CSR build -------------------
__global__ void k_bcount(const int* __restrict__ row, int* __restrict__ bcnt) {
  __shared__ int h[NBUCK];
  for (int i = threadIdx.x; i < NBUCK; i += blockDim.x) h[i] = 0;
  __syncthreads();
  int stride = gridDim.x * blockDim.x;
  for (int i = blockIdx.x * blockDim.x + threadIdx.x; i < NEDGE; i += stride)
    atomicAdd(&h[row[i] >> 7], 1);
  __syncthreads();
  for (int i = threadIdx.x; i < NBUCK; i += blockDim.x)
    if (h[i]) atomicAdd(&bcnt[i], h[i]);
}

__global__ void k_bscan(const int* __restrict__ bcnt, int* __restrict__ bptr,
                        int* __restrict__ bcur) {
  __shared__ int s[1024];
  int tid = threadIdx.x;
  int v = (tid < NBUCK) ? bcnt[tid] : 0;
  s[tid] = v;
  __syncthreads();
  for (int off = 1; off < 1024; off <<= 1) {
    int t = (tid >= off) ? s[tid - off] : 0;
    __syncthreads();
    s[tid] += t;
    __syncthreads();
  }
  if (tid < NBUCK) {
    int ex = s[tid] - v;
    bptr[tid] = ex;
    bcur[tid * 16] = ex;      // padded cursor (own 64B line)
  }
  if (tid == 0) bptr[NBUCK] = NEDGE;
}

__global__ void k_bscatter(const int* __restrict__ row, const int* __restrict__ col,
                           const float* __restrict__ data, int* __restrict__ bcur,
                           uint2* __restrict__ bstage) {
  int stride = gridDim.x * blockDim.x;
  for (int i = blockIdx.x * blockDim.x + threadIdx.x; i < NEDGE; i += stride) {
    int rr = row[i];
    int b = rr >> 7;
    int pos = atomicAdd(&bcur[b * 16], 1);
    bstage[pos] = make_uint2(((unsigned)(rr & (RB - 1)) << 17) | (unsigned)col[i],
                             __float_as_uint(data[i]));
  }
}

__global__ void __launch_bounds__(256) k_bbuild(const int* __restrict__ bptr,
    const uint2* __restrict__ bstage, int* __restrict__ rowptr,
    int2* __restrict__ csr) {
  __shared__ uint2 ebuf[BCAP];
  __shared__ int deg[RB];
  __shared__ int sc[RB];
  __shared__ int cur[RB];
  int b = blockIdx.x;
  int s0 = bptr[b], s1 = bptr[b + 1];
  int n = s1 - s0;
  if (n > BCAP) n = BCAP;     // impossible with this data; memory-safety only
  int tid = threadIdx.x;
  if (tid < RB) deg[tid] = 0;
  __syncthreads();
  for (int i = tid; i < n; i += 256) {
    uint2 e = bstage[s0 + i];
    ebuf[i] = e;
    atomicAdd(&deg[e.x >> 17], 1);
  }
  __syncthreads();
  if (tid < RB) sc[tid] = deg[tid];
  __syncthreads();
  for (int off = 1; off < RB; off <<= 1) {
    int t = 0;
    if (tid >= off && tid < RB) t = sc[tid - off];
    __syncthreads();
    if (tid < RB) sc[tid] += t;
    __syncthreads();
  }
  if (tid < RB) {
    int ex = sc[tid] - deg[tid];
    cur[tid] = ex;
    int grow = b * RB + tid;
    if (grow < NNODE) rowptr[grow] = s0 + ex;
  }
  if (b == 0 && tid == 0) rowptr[NNODE] = NEDGE;
  __syncthreads();
  for (int i = tid; i < n; i += 256) {
    uint2 e = ebuf[i];
    int lr = e.x >> 17;
    int pos = atomicAdd(&cur[lr], 1);
    csr[s0 + pos] = make_int2((int)(e.x & 0x1FFFF), (int)e.y);
  }
}

// ------------------- init: b_vec = X@W + b; x=0; r=p=b_vec; <b,b> partials ---
__global__ void __launch_bounds__(256) k_gemm(const float* __restrict__ feat,
    const float* __restrict__ W, const float* __restrict__ bias,
    float* __restrict__ x, float* __restrict__ r, float* __restrict__ p,
    float* __restrict__ part) {
  __shared__ float ftile[GEMM_ROWS][GEMM_KC + 1];
  __shared__ float red[256];
  int tid = threadIdx.x;
  int r0 = blockIdx.x * GEMM_ROWS;
  float acc[NCLS];
  #pragma unroll
  for (int c = 0; c < NCLS; ++c) acc[c] = bias[c];

  for (int k0 = 0; k0 < DFEAT; k0 += GEMM_KC) {
    __syncthreads();
    #pragma unroll
    for (int it = 0; it < (GEMM_ROWS * GEMM_KC / 4) / 256; ++it) {
      int i = tid + it * 256;
      int rr = i >> 3, kq = i & 7;
      int grow = r0 + rr;
      float4 v = make_float4(0.f, 0.f, 0.f, 0.f);
      if (grow < NNODE)
        v = *(const float4*)(feat + (size_t)grow * DFEAT + k0 + kq * 4);
      ftile[rr][kq * 4 + 0] = v.x;
      ftile[rr][kq * 4 + 1] = v.y;
      ftile[rr][kq * 4 + 2] = v.z;
      ftile[rr][kq * 4 + 3] = v.w;
    }
    __syncthreads();
    #pragma unroll 2
    for (int kk = 0; kk < GEMM_KC; ++kk) {
      float f = ftile[tid][kk];
      const float* wrow = W + (k0 + kk) * NCLS;   // uniform -> scalar loads
      #pragma unroll
      for (int c = 0; c < NCLS; ++c) acc[c] = fmaf(f, wrow[c], acc[c]);
    }
  }

  int grow = r0 + tid;
  float local = 0.f;
  if (grow < NNODE) {
    size_t base = (size_t)grow * NCLS;
    #pragma unroll
    for (int c = 0; c < NCLS; ++c) {
      float a = acc[c];
      r[base + c] = a;
      p[base + c] = a;
      x[base + c] = 0.f;
      local = fmaf(a, a, local);
    }
  }
  float tot = block_reduce_256(local, red);
  if (tid == 0) part[blockIdx.x] = tot;
}

// scalars: scal[0]=omega(=1-eps), scal[1]=atol2, scal[2+k]=gamma_k
__global__ void k_init_scal(const float* __restrict__ part, const float* __restrict__ e0,
                            float* __restrict__ scal) {
  __shared__ float red[256];
  float local = 0.f;
  for (int i = threadIdx.x; i < GEMM_B; i += 256) local += part[i];
  float bs = block_reduce_256(local, red);
  if (threadIdx.x == 0) {
    float eps = 1.f / (1.f + expf(-e0[0]));
    scal[0] = 1.f - eps;
    scal[1] = TOLSQ * bs;
    scal[2] = bs;          // gamma_0 = <r0,r0> = <b,b>
  }
}

// ------------------- CG iteration kernels (device-side convergence guard) ---
__global__ void __launch_bounds__(VT) k_spmv(const float* __restrict__ scal, int k,
    const int* __restrict__ rowptr, const int2* __restrict__ csr,
    const float* __restrict__ p, float* __restrict__ Ap, float* __restrict__ part) {
  float gamma = scal[2 + k], atol2 = scal[1];
  if (!(gamma > atol2)) return;               // mirrors JAX while cond (rs > atol2)
  float omega = scal[0];
  float local = 0.f;
  int stride = gridDim.x * blockDim.x;
  for (int e = blockIdx.x * blockDim.x + threadIdx.x; e < NC_TOT; e += stride) {
    int rr = e / NCLS;
    int c = e - rr * NCLS;
    int s0 = rowptr[rr], s1 = rowptr[rr + 1];
    float acc = 0.f;
    #pragma unroll 4
    for (int j = s0; j < s1; ++j) {
      int2 pr = csr[j];
      acc = fmaf(__int_as_float(pr.y), p[pr.x * NCLS + c], acc);
    }
    float pe = p[e];
    float v = fmaf(-omega, acc, pe);          // f(p) = p - (1-eps) * A p
    Ap[e] = v;
    local = fmaf(pe, v, local);               // <p, Ap> partial
  }
  __shared__ float red[256];
  float tot = block_reduce_256(local, red);
  if (threadIdx.x == 0) part[blockIdx.x] = tot;
}

__global__ void __launch_bounds__(VT) k_xr(const float* __restrict__ scal, int k,
    const float* __restrict__ part_in,
    const float* __restrict__ p, const float* __restrict__ Ap,
    float* __restrict__ x, float* __restrict__ r, float* __restrict__ part_out) {
  float gamma = scal[2 + k], atol2 = scal[1];
  if (!(gamma > atol2)) return;
  __shared__ float red[256];
  float lp = 0.f;
  for (int i = threadIdx.x; i < VB; i += VT) lp += part_in[i];
  float pap = block_reduce_256(lp, red);      // identical in every block
  float alpha = gamma / pap;
  float local = 0.f;
  int stride = gridDim.x * blockDim.x;
  for (int e = blockIdx.x * blockDim.x + threadIdx.x; e < NC_TOT; e += stride) {
    x[e] = fmaf(alpha, p[e], x[e]);
    float rn = fmaf(-alpha, Ap[e], r[e]);
    r[e] = rn;
    local = fmaf(rn, rn, local);              // <r',r'> partial
  }
  float tot = block_reduce_256(local, red);
  if (threadIdx.x == 0) part_out[blockIdx.x] = tot;
}

__global__ void __launch_bounds__(VT) k_pupd(float* __restrict__ scal, int k,
    const float* __restrict__ part_in,
    const float* __restrict__ r, float* __restrict__ p) {
  float gamma = scal[2 + k], atol2 = scal[1];
  if (!(gamma > atol2)) {
    if (blockIdx.x == 0 && threadIdx.x == 0) scal[2 + k + 1] = gamma;  // propagate
    return;
  }
  __shared__ float red[256];
  float lp = 0.f;
  for (int i = threadIdx.x; i < VB; i += VT) lp += part_in[i];
  float gnew = block_reduce_256(lp, red);
  float beta = gnew / gamma;
  int stride = gridDim.x * blockDim.x;
  for (int e = blockIdx.x * blockDim.x + threadIdx.x; e < NC_TOT; e += stride)
    p[e] = fmaf(beta, p[e], r[e]);
  if (blockIdx.x == 0 && threadIdx.x == 0) scal[2 + k + 1] = gnew;
}

__global__ void k_out(const float* __restrict__ x, const int* __restrict__ ids,
                      float* __restrict__ out) {
  int j = blockIdx.x * blockDim.x + threadIdx.x;
  if (j < NIDS * NCLS) {
    int i = j / NCLS, c = j - (j / NCLS) * NCLS;
    out[j] = x[(size_t)ids[i] * NCLS + c];
  }
}

// ------------------- host launch -------------------
extern "C" void kernel_launch(void* const* d_in, const int* in_sizes, int n_in,
                              void* d_out, int out_size, void* d_ws, size_t ws_size,
                              hipStream_t stream) {
  const float* feat = (const float*)d_in[0];
  const float* W    = (const float*)d_in[1];
  const float* bias = (const float*)d_in[2];
  const float* e0   = (const float*)d_in[3];
  const float* data = (const float*)d_in[4];
  const int*   row  = (const int*)d_in[5];
  const int*   col  = (const int*)d_in[6];
  const int*   ids  = (const int*)d_in[7];
  float* out = (float*)d_out;

  size_t off = 0;
  char* base = (char*)d_ws;
  auto take = [&](size_t nbytes) -> void* {
    void* ptr = base + off;
    off += (nbytes + 255) & ~(size_t)255;
    return ptr;
  };
  float* x   = (float*)take((size_t)NC_TOT * 4);
  float* rv  = (float*)take((size_t)NC_TOT * 4);
  float* pv  = (float*)take((size_t)NC_TOT * 4);
  float* ap  = (float*)take((size_t)NC_TOT * 4);
  int2*  csr = (int2*)take((size_t)NEDGE * 8);
  int* rowptr    = (int*)take((size_t)(NNODE + 1) * 4);
  int* bcnt      = (int*)take((size_t)(NBUCK + 2) * 4);
  int* bptr      = (int*)take((size_t)(NBUCK + 2) * 4);
  int* bcur      = (int*)take((size_t)NBUCK * 16 * 4);  // padded cursors
  float* part_a  = (float*)take(VB * 4);
  float* part_b  = (float*)take(VB * 4);
  float* scal    = (float*)take(64 * 4);

  // bucket staging buffer aliases x+rv (25.6MB <= 30.5MB); only live before k_gemm
  uint2* bstage = (uint2*)x;

  // bucketed CSR build
  hipMemsetAsync(bcnt, 0, (size_t)(NBUCK + 2) * 4, stream);
  k_bcount<<<256, 256, 0, stream>>>(row, bcnt);
  k_bscan<<<1, 1024, 0, stream>>>(bcnt, bptr, bcur);
  k_bscatter<<<2048, 256, 0, stream>>>(row, col, data, bcur, bstage);
  k_bbuild<<<NBUCK, 256, 0, stream>>>(bptr, bstage, rowptr, csr);

  // init: b_vec, x0=0, r0=p0=b_vec, gamma0=<b,b>  (overwrites bstage region)
  k_gemm<<<GEMM_B, 256, 0, stream>>>(feat, W, bias, x, rv, pv, part_a);
  k_init_scal<<<1, 256, 0, stream>>>(part_a, e0, scal);

  // 16 unrolled, device-guarded CG iterations
  for (int k = 0; k < MAXIT; ++k) {
    k_spmv<<<VB, VT, 0, stream>>>(scal, k, rowptr, csr, pv, ap, part_a);
    k_xr  <<<VB, VT, 0, stream>>>(scal, k, part_a, pv, ap, x, rv, part_b);
    k_pupd<<<VB, VT, 0, stream>>>(scal, k, part_b, rv, pv);
  }

  k_out<<<(NIDS * NCLS + 255) / 256, 256, 0, stream>>>(x, ids, out);
}

// Round 3
// 627.001 us; speedup vs baseline: 1.4567x; 1.1724x over previous
//
#include <hip/hip_runtime.h>
#include <math.h>

// Problem constants (from reference)
#define NNODE  100000
#define NEDGE  3200000
#define DFEAT  256
#define NCLS   40
#define NC_TOT 4000000        // NNODE * NCLS
#define NIDS   1000
#define TOLSQ  1.0e-4f        // TOL^2, TOL = 0.01
#define MAXIT  16

#define VB 1024               // blocks for vector-length kernels
#define VT 256
#define GEMM_ROWS 256
#define GEMM_KC   32
#define GEMM_B    391         // ceil(NNODE / GEMM_ROWS)

// Bucketed CSR build
#define RB      128           // rows per bucket (row >> 7)
#define NBUCK   782           // ceil(NNODE / RB)
#define BCAP    6144          // LDS edge capacity per bucket in k_bbuild
// Partition (counting sort) parameters
#define NPB     800           // partition blocks
#define EPB     4000          // edges per partition block (NPB*EPB == NEDGE)

__device__ __forceinline__ float block_reduce_256(float v, float* red) {
  int tid = threadIdx.x;
  red[tid] = v;
  __syncthreads();
  #pragma unroll
  for (int off = 128; off > 0; off >>= 1) {
    if (tid < off) red[tid] += red[tid + off];
    __syncthreads();
  }
  float res = red[0];
  __syncthreads();
  return res;
}

// ------------------- partition-based CSR build -------------------
// Phase 1: per-block bucket histogram -> cntmat[blk][bucket]
__global__ void __launch_bounds__(256) k_pcount(const int* __restrict__ row,
                                                int* __restrict__ cntmat) {
  __shared__ int h[NBUCK];
  int tid = threadIdx.x, blk = blockIdx.x;
  for (int i = tid; i < NBUCK; i += 256) h[i] = 0;
  __syncthreads();
  int e0 = blk * EPB;
  for (int i = tid; i < EPB; i += 256) atomicAdd(&h[row[e0 + i] >> 7], 1);
  __syncthreads();
  for (int i = tid; i < NBUCK; i += 256) cntmat[blk * NBUCK + i] = h[i];
}

// Phase 2a: bucket totals
__global__ void k_ctot(const int* __restrict__ cntmat, int* __restrict__ total) {
  int blk = blockIdx.x, tid = threadIdx.x;
  for (int i = tid; i < NBUCK; i += 256)
    atomicAdd(&total[i], cntmat[blk * NBUCK + i]);
}

// Phase 2b: exclusive scan of totals -> bptr
__global__ void k_bscan2(const int* __restrict__ total, int* __restrict__ bptr) {
  __shared__ int s[1024];
  int tid = threadIdx.x;
  int v = (tid < NBUCK) ? total[tid] : 0;
  s[tid] = v;
  __syncthreads();
  for (int off = 1; off < 1024; off <<= 1) {
    int t = (tid >= off) ? s[tid - off] : 0;
    __syncthreads();
    s[tid] += t;
    __syncthreads();
  }
  if (tid < NBUCK) bptr[tid] = s[tid] - v;
  if (tid == 0) bptr[NBUCK] = NEDGE;
}

// Phase 2c: per-bucket scan over blocks: offmat[blk][bucket] (in-place on cntmat)
__global__ void __launch_bounds__(1024) k_colscan(int* __restrict__ cntmat,
                                                  const int* __restrict__ bptr) {
  __shared__ int s[1024];
  int b = blockIdx.x;           // bucket
  int tid = threadIdx.x;        // block index along partition axis
  int v = (tid < NPB) ? cntmat[tid * NBUCK + b] : 0;
  s[tid] = v;
  __syncthreads();
  for (int off = 1; off < 1024; off <<= 1) {
    int t = (tid >= off) ? s[tid - off] : 0;
    __syncthreads();
    s[tid] += t;
    __syncthreads();
  }
  if (tid < NPB) cntmat[tid * NBUCK + b] = bptr[b] + s[tid] - v;
}

// Phase 3: in-LDS counting sort per block, contiguous coalesced write-out
__global__ void __launch_bounds__(256) k_ppart(const int* __restrict__ row,
    const int* __restrict__ col, const float* __restrict__ data,
    const int* __restrict__ offmat, uint2* __restrict__ bstage) {
  __shared__ int cnt[NBUCK];
  __shared__ int segs[NBUCK + 1];
  __shared__ int cur[NBUCK];
  __shared__ int goff[NBUCK];
  __shared__ int scp[256];
  __shared__ unsigned short bof[EPB];
  __shared__ uint2 pay[EPB];
  int tid = threadIdx.x, blk = blockIdx.x;
  int e0 = blk * EPB;

  for (int i = tid; i < NBUCK; i += 256) {
    cnt[i] = 0;
    goff[i] = offmat[blk * NBUCK + i];
  }
  __syncthreads();
  for (int i = tid; i < EPB; i += 256) atomicAdd(&cnt[row[e0 + i] >> 7], 1);
  __syncthreads();

  // exclusive scan cnt[0..NBUCK) -> segs, via 4-per-thread + block scan
  int t4 = tid * 4;
  int l0 = (t4 + 0 < NBUCK) ? cnt[t4 + 0] : 0;
  int l1 = (t4 + 1 < NBUCK) ? cnt[t4 + 1] : 0;
  int l2 = (t4 + 2 < NBUCK) ? cnt[t4 + 2] : 0;
  int l3 = (t4 + 3 < NBUCK) ? cnt[t4 + 3] : 0;
  int mysum = l0 + l1 + l2 + l3;
  scp[tid] = mysum;
  __syncthreads();
  for (int off = 1; off < 256; off <<= 1) {
    int t = (tid >= off) ? scp[tid - off] : 0;
    __syncthreads();
    scp[tid] += t;
    __syncthreads();
  }
  int base = scp[tid] - mysum;   // exclusive prefix for element t4
  if (t4 + 0 <= NBUCK) segs[t4 + 0] = base;  base += l0;
  if (t4 + 1 <= NBUCK) segs[t4 + 1] = base;  base += l1;
  if (t4 + 2 <= NBUCK) segs[t4 + 2] = base;  base += l2;
  if (t4 + 3 <= NBUCK) segs[t4 + 3] = base;
  for (int i = tid; i < NBUCK; i += 256) cur[i] = 0;
  __syncthreads();

  // inverse map: bucket_of[lds_pos]
  for (int b = tid; b < NBUCK; b += 256) {
    int s1 = segs[b + 1];
    for (int i = segs[b]; i < s1; ++i) bof[i] = (unsigned short)b;
  }
  // LDS counting-sort scatter
  for (int i = tid; i < EPB; i += 256) {
    int rr = row[e0 + i];
    int b = rr >> 7;
    int rk = atomicAdd(&cur[b], 1);
    pay[segs[b] + rk] = make_uint2(((unsigned)(rr & (RB - 1)) << 17) | (unsigned)col[e0 + i],
                                   __float_as_uint(data[e0 + i]));
  }
  __syncthreads();
  // linear write-out: each bucket segment contiguous in global stage
  for (int i = tid; i < EPB; i += 256) {
    int b = bof[i];
    bstage[goff[b] + (i - segs[b])] = pay[i];
  }
}

__global__ void __launch_bounds__(256) k_bbuild(const int* __restrict__ bptr,
    const uint2* __restrict__ bstage, int* __restrict__ rowptr,
    int2* __restrict__ csr) {
  __shared__ uint2 ebuf[BCAP];
  __shared__ int deg[RB];
  __shared__ int sc[RB];
  __shared__ int cur[RB];
  int b = blockIdx.x;
  int s0 = bptr[b], s1 = bptr[b + 1];
  int n = s1 - s0;
  if (n > BCAP) n = BCAP;     // impossible with this data; memory-safety only
  int tid = threadIdx.x;
  if (tid < RB) deg[tid] = 0;
  __syncthreads();
  for (int i = tid; i < n; i += 256) {
    uint2 e = bstage[s0 + i];
    ebuf[i] = e;
    atomicAdd(&deg[e.x >> 17], 1);
  }
  __syncthreads();
  if (tid < RB) sc[tid] = deg[tid];
  __syncthreads();
  for (int off = 1; off < RB; off <<= 1) {
    int t = 0;
    if (tid >= off && tid < RB) t = sc[tid - off];
    __syncthreads();
    if (tid < RB) sc[tid] += t;
    __syncthreads();
  }
  if (tid < RB) {
    int ex = sc[tid] - deg[tid];
    cur[tid] = ex;
    int grow = b * RB + tid;
    if (grow < NNODE) rowptr[grow] = s0 + ex;
  }
  if (b == 0 && tid == 0) rowptr[NNODE] = NEDGE;
  __syncthreads();
  for (int i = tid; i < n; i += 256) {
    uint2 e = ebuf[i];
    int lr = e.x >> 17;
    int pos = atomicAdd(&cur[lr], 1);
    csr[s0 + pos] = make_int2((int)(e.x & 0x1FFFF), (int)e.y);
  }
}

// ------------------- init: b_vec = X@W + b; x=0; r=p=b_vec; <b,b> partials ---
__global__ void __launch_bounds__(256) k_gemm(const float* __restrict__ feat,
    const float* __restrict__ W, const float* __restrict__ bias,
    float* __restrict__ x, float* __restrict__ r, float* __restrict__ p,
    float* __restrict__ part) {
  __shared__ float ftile[GEMM_ROWS][GEMM_KC + 1];
  __shared__ float red[256];
  int tid = threadIdx.x;
  int r0 = blockIdx.x * GEMM_ROWS;
  float acc[NCLS];
  #pragma unroll
  for (int c = 0; c < NCLS; ++c) acc[c] = bias[c];

  for (int k0 = 0; k0 < DFEAT; k0 += GEMM_KC) {
    __syncthreads();
    #pragma unroll
    for (int it = 0; it < (GEMM_ROWS * GEMM_KC / 4) / 256; ++it) {
      int i = tid + it * 256;
      int rr = i >> 3, kq = i & 7;
      int grow = r0 + rr;
      float4 v = make_float4(0.f, 0.f, 0.f, 0.f);
      if (grow < NNODE)
        v = *(const float4*)(feat + (size_t)grow * DFEAT + k0 + kq * 4);
      ftile[rr][kq * 4 + 0] = v.x;
      ftile[rr][kq * 4 + 1] = v.y;
      ftile[rr][kq * 4 + 2] = v.z;
      ftile[rr][kq * 4 + 3] = v.w;
    }
    __syncthreads();
    #pragma unroll 2
    for (int kk = 0; kk < GEMM_KC; ++kk) {
      float f = ftile[tid][kk];
      const float* wrow = W + (k0 + kk) * NCLS;   // uniform -> scalar loads
      #pragma unroll
      for (int c = 0; c < NCLS; ++c) acc[c] = fmaf(f, wrow[c], acc[c]);
    }
  }

  int grow = r0 + tid;
  float local = 0.f;
  if (grow < NNODE) {
    size_t base = (size_t)grow * NCLS;
    #pragma unroll
    for (int c = 0; c < NCLS; ++c) {
      float a = acc[c];
      r[base + c] = a;
      p[base + c] = a;
      x[base + c] = 0.f;
      local = fmaf(a, a, local);
    }
  }
  float tot = block_reduce_256(local, red);
  if (tid == 0) part[blockIdx.x] = tot;
}

// scalars: scal[0]=omega(=1-eps), scal[1]=atol2, scal[2+k]=gamma_k
__global__ void k_init_scal(const float* __restrict__ part, const float* __restrict__ e0,
                            float* __restrict__ scal) {
  __shared__ float red[256];
  float local = 0.f;
  for (int i = threadIdx.x; i < GEMM_B; i += 256) local += part[i];
  float bs = block_reduce_256(local, red);
  if (threadIdx.x == 0) {
    float eps = 1.f / (1.f + expf(-e0[0]));
    scal[0] = 1.f - eps;
    scal[1] = TOLSQ * bs;
    scal[2] = bs;          // gamma_0 = <r0,r0> = <b,b>
  }
}

// ------------------- CG iteration kernels (device-side convergence guard) ---
__global__ void __launch_bounds__(VT) k_spmv(const float* __restrict__ scal, int k,
    const int* __restrict__ rowptr, const int2* __restrict__ csr,
    const float* __restrict__ p, float* __restrict__ Ap, float* __restrict__ part) {
  float gamma = scal[2 + k], atol2 = scal[1];
  if (!(gamma > atol2)) return;               // mirrors JAX while cond (rs > atol2)
  float omega = scal[0];
  float local = 0.f;
  int stride = gridDim.x * blockDim.x;
  for (int e = blockIdx.x * blockDim.x + threadIdx.x; e < NC_TOT; e += stride) {
    int rr = e / NCLS;
    int c = e - rr * NCLS;
    int s0 = rowptr[rr], s1 = rowptr[rr + 1];
    float acc = 0.f;
    #pragma unroll 4
    for (int j = s0; j < s1; ++j) {
      int2 pr = csr[j];
      acc = fmaf(__int_as_float(pr.y), p[pr.x * NCLS + c], acc);
    }
    float pe = p[e];
    float v = fmaf(-omega, acc, pe);          // f(p) = p - (1-eps) * A p
    Ap[e] = v;
    local = fmaf(pe, v, local);               // <p, Ap> partial
  }
  __shared__ float red[256];
  float tot = block_reduce_256(local, red);
  if (threadIdx.x == 0) part[blockIdx.x] = tot;
}

__global__ void __launch_bounds__(VT) k_xr(const float* __restrict__ scal, int k,
    const float* __restrict__ part_in,
    const float* __restrict__ p, const float* __restrict__ Ap,
    float* __restrict__ x, float* __restrict__ r, float* __restrict__ part_out) {
  float gamma = scal[2 + k], atol2 = scal[1];
  if (!(gamma > atol2)) return;
  __shared__ float red[256];
  float lp = 0.f;
  for (int i = threadIdx.x; i < VB; i += VT) lp += part_in[i];
  float pap = block_reduce_256(lp, red);      // identical in every block
  float alpha = gamma / pap;
  float local = 0.f;
  int stride = gridDim.x * blockDim.x;
  for (int e = blockIdx.x * blockDim.x + threadIdx.x; e < NC_TOT; e += stride) {
    x[e] = fmaf(alpha, p[e], x[e]);
    float rn = fmaf(-alpha, Ap[e], r[e]);
    r[e] = rn;
    local = fmaf(rn, rn, local);              // <r',r'> partial
  }
  float tot = block_reduce_256(local, red);
  if (threadIdx.x == 0) part_out[blockIdx.x] = tot;
}

__global__ void __launch_bounds__(VT) k_pupd(float* __restrict__ scal, int k,
    const float* __restrict__ part_in,
    const float* __restrict__ r, float* __restrict__ p) {
  float gamma = scal[2 + k], atol2 = scal[1];
  if (!(gamma > atol2)) {
    if (blockIdx.x == 0 && threadIdx.x == 0) scal[2 + k + 1] = gamma;  // propagate
    return;
  }
  __shared__ float red[256];
  float lp = 0.f;
  for (int i = threadIdx.x; i < VB; i += VT) lp += part_in[i];
  float gnew = block_reduce_256(lp, red);
  float beta = gnew / gamma;
  int stride = gridDim.x * blockDim.x;
  for (int e = blockIdx.x * blockDim.x + threadIdx.x; e < NC_TOT; e += stride)
    p[e] = fmaf(beta, p[e], r[e]);
  if (blockIdx.x == 0 && threadIdx.x == 0) scal[2 + k + 1] = gnew;
}

__global__ void k_out(const float* __restrict__ x, const int* __restrict__ ids,
                      float* __restrict__ out) {
  int j = blockIdx.x * blockDim.x + threadIdx.x;
  if (j < NIDS * NCLS) {
    int i = j / NCLS, c = j - (j / NCLS) * NCLS;
    out[j] = x[(size_t)ids[i] * NCLS + c];
  }
}

// ------------------- host launch -------------------
extern "C" void kernel_launch(void* const* d_in, const int* in_sizes, int n_in,
                              void* d_out, int out_size, void* d_ws, size_t ws_size,
                              hipStream_t stream) {
  const float* feat = (const float*)d_in[0];
  const float* W    = (const float*)d_in[1];
  const float* bias = (const float*)d_in[2];
  const float* e0   = (const float*)d_in[3];
  const float* data = (const float*)d_in[4];
  const int*   row  = (const int*)d_in[5];
  const int*   col  = (const int*)d_in[6];
  const int*   ids  = (const int*)d_in[7];
  float* out = (float*)d_out;

  size_t off = 0;
  char* base = (char*)d_ws;
  auto take = [&](size_t nbytes) -> void* {
    void* ptr = base + off;
    off += (nbytes + 255) & ~(size_t)255;
    return ptr;
  };
  float* x   = (float*)take((size_t)NC_TOT * 4);
  float* rv  = (float*)take((size_t)NC_TOT * 4);
  float* pv  = (float*)take((size_t)NC_TOT * 4);
  float* ap  = (float*)take((size_t)NC_TOT * 4);
  int2*  csr = (int2*)take((size_t)NEDGE * 8);
  int* rowptr    = (int*)take((size_t)(NNODE + 1) * 4);
  int* cntmat    = (int*)take((size_t)NPB * NBUCK * 4);   // becomes offmat in-place
  int* total     = (int*)take((size_t)(NBUCK + 2) * 4);
  int* bptr      = (int*)take((size_t)(NBUCK + 2) * 4);
  float* part_a  = (float*)take(VB * 4);
  float* part_b  = (float*)take(VB * 4);
  float* scal    = (float*)take(64 * 4);

  // bucket staging buffer aliases x+rv (25.6MB); only live before k_gemm
  uint2* bstage = (uint2*)x;

  // partition-based CSR build
  hipMemsetAsync(total, 0, (size_t)(NBUCK + 2) * 4, stream);
  k_pcount<<<NPB, 256, 0, stream>>>(row, cntmat);
  k_ctot<<<NPB, 256, 0, stream>>>(cntmat, total);
  k_bscan2<<<1, 1024, 0, stream>>>(total, bptr);
  k_colscan<<<NBUCK, 1024, 0, stream>>>(cntmat, bptr);
  k_ppart<<<NPB, 256, 0, stream>>>(row, col, data, cntmat, bstage);
  k_bbuild<<<NBUCK, 256, 0, stream>>>(bptr, bstage, rowptr, csr);

  // init: b_vec, x0=0, r0=p0=b_vec, gamma0=<b,b>  (overwrites bstage region)
  k_gemm<<<GEMM_B, 256, 0, stream>>>(feat, W, bias, x, rv, pv, part_a);
  k_init_scal<<<1, 256, 0, stream>>>(part_a, e0, scal);

  // 16 unrolled, device-guarded CG iterations
  for (int k = 0; k < MAXIT; ++k) {
    k_spmv<<<VB, VT, 0, stream>>>(scal, k, rowptr, csr, pv, ap, part_a);
    k_xr  <<<VB, VT, 0, stream>>>(scal, k, part_a, pv, ap, x, rv, part_b);
    k_pupd<<<VB, VT, 0, stream>>>(scal, k, part_b, rv, pv);
  }

  k_out<<<(NIDS * NCLS + 255) / 256, 256, 0, stream>>>(x, ids, out);
}

// Round 4
// 589.722 us; speedup vs baseline: 1.5488x; 1.0632x over previous
//
#include <hip/hip_runtime.h>
#include <math.h>

// Problem constants (from reference)
#define NNODE  100000
#define NEDGE  3200000
#define DFEAT  256
#define NCLS   40
#define NC_TOT 4000000        // NNODE * NCLS
#define NIDS   1000
#define TOLSQ  1.0e-4f        // TOL^2, TOL = 0.01
#define MAXIT  16

#define VB 1024               // blocks for vector-length kernels
#define VT 256
#define GR     128            // rows per gemm block (2 rows/thread, 4 cslots)
#define GKC    32             // gemm K tile
#define GEMM_B 782            // ceil(NNODE / GR)

// Bucketed CSR build
#define RB      128           // rows per bucket (row >> 7)
#define NBUCK   782           // ceil(NNODE / RB)
#define BCAP    6144          // LDS edge capacity per bucket in k_bbuild
// Partition (counting sort) parameters
#define NPB     800           // partition blocks
#define EPB     4000          // edges per partition block (NPB*EPB == NEDGE)

__device__ __forceinline__ float block_reduce_256(float v, float* red) {
  int tid = threadIdx.x;
  red[tid] = v;
  __syncthreads();
  #pragma unroll
  for (int off = 128; off > 0; off >>= 1) {
    if (tid < off) red[tid] += red[tid + off];
    __syncthreads();
  }
  float res = red[0];
  __syncthreads();
  return res;
}

// ------------------- partition-based CSR build -------------------
// Phase 1: per-block bucket histogram -> cntmat[blk][bucket] (+ global totals)
__global__ void __launch_bounds__(256) k_pcount(const int* __restrict__ row,
                                                int* __restrict__ cntmat,
                                                int* __restrict__ total) {
  __shared__ int h[NBUCK];
  int tid = threadIdx.x, blk = blockIdx.x;
  for (int i = tid; i < NBUCK; i += 256) h[i] = 0;
  __syncthreads();
  int e0 = blk * EPB;
  for (int i = tid; i < EPB; i += 256) atomicAdd(&h[row[e0 + i] >> 7], 1);
  __syncthreads();
  for (int i = tid; i < NBUCK; i += 256) {
    int v = h[i];
    cntmat[blk * NBUCK + i] = v;
    if (v) atomicAdd(&total[i], v);
  }
}

// Phase 2b: exclusive scan of totals -> bptr
__global__ void k_bscan2(const int* __restrict__ total, int* __restrict__ bptr) {
  __shared__ int s[1024];
  int tid = threadIdx.x;
  int v = (tid < NBUCK) ? total[tid] : 0;
  s[tid] = v;
  __syncthreads();
  for (int off = 1; off < 1024; off <<= 1) {
    int t = (tid >= off) ? s[tid - off] : 0;
    __syncthreads();
    s[tid] += t;
    __syncthreads();
  }
  if (tid < NBUCK) bptr[tid] = s[tid] - v;
  if (tid == 0) bptr[NBUCK] = NEDGE;
}

// Phase 2c: per-bucket scan over blocks: offmat[blk][bucket] (in-place on cntmat)
__global__ void __launch_bounds__(1024) k_colscan(int* __restrict__ cntmat,
                                                  const int* __restrict__ bptr) {
  __shared__ int s[1024];
  int b = blockIdx.x;           // bucket
  int tid = threadIdx.x;        // block index along partition axis
  int v = (tid < NPB) ? cntmat[tid * NBUCK + b] : 0;
  s[tid] = v;
  __syncthreads();
  for (int off = 1; off < 1024; off <<= 1) {
    int t = (tid >= off) ? s[tid - off] : 0;
    __syncthreads();
    s[tid] += t;
    __syncthreads();
  }
  if (tid < NPB) cntmat[tid * NBUCK + b] = bptr[b] + s[tid] - v;
}

// Phase 3: in-LDS counting sort per block, contiguous coalesced write-out
__global__ void __launch_bounds__(256) k_ppart(const int* __restrict__ row,
    const int* __restrict__ col, const float* __restrict__ data,
    const int* __restrict__ offmat, uint2* __restrict__ bstage) {
  __shared__ int cnt[NBUCK];
  __shared__ int segs[NBUCK + 1];
  __shared__ int cur[NBUCK];
  __shared__ int goff[NBUCK];
  __shared__ int scp[256];
  __shared__ unsigned short bof[EPB];
  __shared__ uint2 pay[EPB];
  int tid = threadIdx.x, blk = blockIdx.x;
  int e0 = blk * EPB;

  for (int i = tid; i < NBUCK; i += 256) {
    cnt[i] = 0;
    goff[i] = offmat[blk * NBUCK + i];
  }
  __syncthreads();
  for (int i = tid; i < EPB; i += 256) atomicAdd(&cnt[row[e0 + i] >> 7], 1);
  __syncthreads();

  // exclusive scan cnt[0..NBUCK) -> segs, via 4-per-thread + block scan
  int t4 = tid * 4;
  int l0 = (t4 + 0 < NBUCK) ? cnt[t4 + 0] : 0;
  int l1 = (t4 + 1 < NBUCK) ? cnt[t4 + 1] : 0;
  int l2 = (t4 + 2 < NBUCK) ? cnt[t4 + 2] : 0;
  int l3 = (t4 + 3 < NBUCK) ? cnt[t4 + 3] : 0;
  int mysum = l0 + l1 + l2 + l3;
  scp[tid] = mysum;
  __syncthreads();
  for (int off = 1; off < 256; off <<= 1) {
    int t = (tid >= off) ? scp[tid - off] : 0;
    __syncthreads();
    scp[tid] += t;
    __syncthreads();
  }
  int base = scp[tid] - mysum;   // exclusive prefix for element t4
  if (t4 + 0 <= NBUCK) segs[t4 + 0] = base;  base += l0;
  if (t4 + 1 <= NBUCK) segs[t4 + 1] = base;  base += l1;
  if (t4 + 2 <= NBUCK) segs[t4 + 2] = base;  base += l2;
  if (t4 + 3 <= NBUCK) segs[t4 + 3] = base;
  for (int i = tid; i < NBUCK; i += 256) cur[i] = 0;
  __syncthreads();

  // inverse map: bucket_of[lds_pos]
  for (int b = tid; b < NBUCK; b += 256) {
    int s1 = segs[b + 1];
    for (int i = segs[b]; i < s1; ++i) bof[i] = (unsigned short)b;
  }
  // LDS counting-sort scatter
  for (int i = tid; i < EPB; i += 256) {
    int rr = row[e0 + i];
    int b = rr >> 7;
    int rk = atomicAdd(&cur[b], 1);
    pay[segs[b] + rk] = make_uint2(((unsigned)(rr & (RB - 1)) << 17) | (unsigned)col[e0 + i],
                                   __float_as_uint(data[e0 + i]));
  }
  __syncthreads();
  // linear write-out: each bucket segment contiguous in global stage
  for (int i = tid; i < EPB; i += 256) {
    int b = bof[i];
    bstage[goff[b] + (i - segs[b])] = pay[i];
  }
}

__global__ void __launch_bounds__(256) k_bbuild(const int* __restrict__ bptr,
    const uint2* __restrict__ bstage, int* __restrict__ rowptr,
    int2* __restrict__ csr) {
  __shared__ uint2 ebuf[BCAP];
  __shared__ int deg[RB];
  __shared__ int sc[RB];
  __shared__ int cur[RB];
  int b = blockIdx.x;
  int s0 = bptr[b], s1 = bptr[b + 1];
  int n = s1 - s0;
  if (n > BCAP) n = BCAP;     // impossible with this data; memory-safety only
  int tid = threadIdx.x;
  if (tid < RB) deg[tid] = 0;
  __syncthreads();
  for (int i = tid; i < n; i += 256) {
    uint2 e = bstage[s0 + i];
    ebuf[i] = e;
    atomicAdd(&deg[e.x >> 17], 1);
  }
  __syncthreads();
  if (tid < RB) sc[tid] = deg[tid];
  __syncthreads();
  for (int off = 1; off < RB; off <<= 1) {
    int t = 0;
    if (tid >= off && tid < RB) t = sc[tid - off];
    __syncthreads();
    if (tid < RB) sc[tid] += t;
    __syncthreads();
  }
  if (tid < RB) {
    int ex = sc[tid] - deg[tid];
    cur[tid] = ex;
    int grow = b * RB + tid;
    if (grow < NNODE) rowptr[grow] = s0 + ex;
  }
  if (b == 0 && tid == 0) rowptr[NNODE] = NEDGE;
  __syncthreads();
  for (int i = tid; i < n; i += 256) {
    uint2 e = ebuf[i];
    int lr = e.x >> 17;
    int pos = atomicAdd(&cur[lr], 1);
    csr[s0 + pos] = make_int2((int)(e.x & 0x1FFFF), (int)e.y);
  }
}

// ------------------- init: b_vec = X@W + b; x=0; r=p=b_vec; <b,b> partials ---
// 128 rows/block, 256 threads: thread owns 2 rows x 10 classes.
__global__ void __launch_bounds__(256) k_gemm(const float* __restrict__ feat,
    const float* __restrict__ W, const float* __restrict__ bias,
    float* __restrict__ x, float* __restrict__ r, float* __restrict__ p,
    float* __restrict__ part) {
  __shared__ float ftile[GR][GKC + 1];   // 128*33*4 = 16896 B, bank-conflict-free
  __shared__ float wtile[GKC * NCLS];    // 5120 B
  __shared__ float red[256];
  int tid = threadIdx.x;
  int r0 = blockIdx.x * GR;
  int rl0 = (tid >> 2) * 2;              // this thread's two local rows
  int cbase = (tid & 3) * 10;            // this thread's class slice
  float acc0[10], acc1[10];
  #pragma unroll
  for (int j = 0; j < 10; ++j) {
    float bv = bias[cbase + j];
    acc0[j] = bv;
    acc1[j] = bv;
  }

  for (int k0 = 0; k0 < DFEAT; k0 += GKC) {
    __syncthreads();
    // stage 128x32 feature tile (1024 float4, 4 per thread)
    #pragma unroll
    for (int it = 0; it < 4; ++it) {
      int i = tid + it * 256;
      int rr = i >> 3, kq = i & 7;
      int grow = r0 + rr;
      float4 v = make_float4(0.f, 0.f, 0.f, 0.f);
      if (grow < NNODE)
        v = *(const float4*)(feat + (size_t)grow * DFEAT + k0 + kq * 4);
      ftile[rr][kq * 4 + 0] = v.x;
      ftile[rr][kq * 4 + 1] = v.y;
      ftile[rr][kq * 4 + 2] = v.z;
      ftile[rr][kq * 4 + 3] = v.w;
    }
    // stage 32x40 W tile (1280 floats, 5 per thread), coalesced
    #pragma unroll
    for (int it = 0; it < 5; ++it) {
      int i = tid + it * 256;
      wtile[i] = W[k0 * NCLS + i];
    }
    __syncthreads();
    #pragma unroll 4
    for (int kk = 0; kk < GKC; ++kk) {
      float f0 = ftile[rl0][kk];
      float f1 = ftile[rl0 + 1][kk];
      const float* wr = &wtile[kk * NCLS + cbase];
      #pragma unroll
      for (int j = 0; j < 10; ++j) {
        float w = wr[j];
        acc0[j] = fmaf(f0, w, acc0[j]);
        acc1[j] = fmaf(f1, w, acc1[j]);
      }
    }
  }

  float local = 0.f;
  int g0 = r0 + rl0, g1 = g0 + 1;
  if (g0 < NNODE) {
    size_t b0 = (size_t)g0 * NCLS + cbase;
    #pragma unroll
    for (int j = 0; j < 10; ++j) {
      float a = acc0[j];
      r[b0 + j] = a; p[b0 + j] = a; x[b0 + j] = 0.f;
      local = fmaf(a, a, local);
    }
  }
  if (g1 < NNODE) {
    size_t b1 = (size_t)g1 * NCLS + cbase;
    #pragma unroll
    for (int j = 0; j < 10; ++j) {
      float a = acc1[j];
      r[b1 + j] = a; p[b1 + j] = a; x[b1 + j] = 0.f;
      local = fmaf(a, a, local);
    }
  }
  float tot = block_reduce_256(local, red);
  if (tid == 0) part[blockIdx.x] = tot;
}

// scalars: scal[0]=omega(=1-eps), scal[1]=atol2, scal[2+k]=gamma_k
__global__ void k_init_scal(const float* __restrict__ part, const float* __restrict__ e0,
                            float* __restrict__ scal) {
  __shared__ float red[256];
  float local = 0.f;
  for (int i = threadIdx.x; i < GEMM_B; i += 256) local += part[i];
  float bs = block_reduce_256(local, red);
  if (threadIdx.x == 0) {
    float eps = 1.f / (1.f + expf(-e0[0]));
    scal[0] = 1.f - eps;
    scal[1] = TOLSQ * bs;
    scal[2] = bs;          // gamma_0 = <r0,r0> = <b,b>
  }
}

// ------------------- CG iteration kernels (device-side convergence guard) ---
__global__ void __launch_bounds__(VT) k_spmv(const float* __restrict__ scal, int k,
    const int* __restrict__ rowptr, const int2* __restrict__ csr,
    const float* __restrict__ p, float* __restrict__ Ap, float* __restrict__ part) {
  float gamma = scal[2 + k], atol2 = scal[1];
  if (!(gamma > atol2)) return;               // mirrors JAX while cond (rs > atol2)
  float omega = scal[0];
  float local = 0.f;
  int stride = gridDim.x * blockDim.x;
  for (int e = blockIdx.x * blockDim.x + threadIdx.x; e < NC_TOT; e += stride) {
    int rr = e / NCLS;
    int c = e - rr * NCLS;
    int s0 = rowptr[rr], s1 = rowptr[rr + 1];
    float acc = 0.f;
    #pragma unroll 4
    for (int j = s0; j < s1; ++j) {
      int2 pr = csr[j];
      acc = fmaf(__int_as_float(pr.y), p[pr.x * NCLS + c], acc);
    }
    float pe = p[e];
    float v = fmaf(-omega, acc, pe);          // f(p) = p - (1-eps) * A p
    Ap[e] = v;
    local = fmaf(pe, v, local);               // <p, Ap> partial
  }
  __shared__ float red[256];
  float tot = block_reduce_256(local, red);
  if (threadIdx.x == 0) part[blockIdx.x] = tot;
}

__global__ void __launch_bounds__(VT) k_xr(const float* __restrict__ scal, int k,
    const float* __restrict__ part_in,
    const float* __restrict__ p, const float* __restrict__ Ap,
    float* __restrict__ x, float* __restrict__ r, float* __restrict__ part_out) {
  float gamma = scal[2 + k], atol2 = scal[1];
  if (!(gamma > atol2)) return;
  __shared__ float red[256];
  float lp = 0.f;
  for (int i = threadIdx.x; i < VB; i += VT) lp += part_in[i];
  float pap = block_reduce_256(lp, red);      // identical in every block
  float alpha = gamma / pap;
  float local = 0.f;
  int stride = gridDim.x * blockDim.x;
  for (int e = blockIdx.x * blockDim.x + threadIdx.x; e < NC_TOT; e += stride) {
    x[e] = fmaf(alpha, p[e], x[e]);
    float rn = fmaf(-alpha, Ap[e], r[e]);
    r[e] = rn;
    local = fmaf(rn, rn, local);              // <r',r'> partial
  }
  float tot = block_reduce_256(local, red);
  if (threadIdx.x == 0) part_out[blockIdx.x] = tot;
}

__global__ void __launch_bounds__(VT) k_pupd(float* __restrict__ scal, int k,
    const float* __restrict__ part_in,
    const float* __restrict__ r, float* __restrict__ p) {
  float gamma = scal[2 + k], atol2 = scal[1];
  if (!(gamma > atol2)) {
    if (blockIdx.x == 0 && threadIdx.x == 0) scal[2 + k + 1] = gamma;  // propagate
    return;
  }
  __shared__ float red[256];
  float lp = 0.f;
  for (int i = threadIdx.x; i < VB; i += VT) lp += part_in[i];
  float gnew = block_reduce_256(lp, red);
  float beta = gnew / gamma;
  int stride = gridDim.x * blockDim.x;
  for (int e = blockIdx.x * blockDim.x + threadIdx.x; e < NC_TOT; e += stride)
    p[e] = fmaf(beta, p[e], r[e]);
  if (blockIdx.x == 0 && threadIdx.x == 0) scal[2 + k + 1] = gnew;
}

__global__ void k_out(const float* __restrict__ x, const int* __restrict__ ids,
                      float* __restrict__ out) {
  int j = blockIdx.x * blockDim.x + threadIdx.x;
  if (j < NIDS * NCLS) {
    int i = j / NCLS, c = j - (j / NCLS) * NCLS;
    out[j] = x[(size_t)ids[i] * NCLS + c];
  }
}

// ------------------- host launch -------------------
extern "C" void kernel_launch(void* const* d_in, const int* in_sizes, int n_in,
                              void* d_out, int out_size, void* d_ws, size_t ws_size,
                              hipStream_t stream) {
  const float* feat = (const float*)d_in[0];
  const float* W    = (const float*)d_in[1];
  const float* bias = (const float*)d_in[2];
  const float* e0   = (const float*)d_in[3];
  const float* data = (const float*)d_in[4];
  const int*   row  = (const int*)d_in[5];
  const int*   col  = (const int*)d_in[6];
  const int*   ids  = (const int*)d_in[7];
  float* out = (float*)d_out;

  size_t off = 0;
  char* base = (char*)d_ws;
  auto take = [&](size_t nbytes) -> void* {
    void* ptr = base + off;
    off += (nbytes + 255) & ~(size_t)255;
    return ptr;
  };
  float* x   = (float*)take((size_t)NC_TOT * 4);
  float* rv  = (float*)take((size_t)NC_TOT * 4);
  float* pv  = (float*)take((size_t)NC_TOT * 4);
  float* ap  = (float*)take((size_t)NC_TOT * 4);
  int2*  csr = (int2*)take((size_t)NEDGE * 8);
  int* rowptr    = (int*)take((size_t)(NNODE + 1) * 4);
  int* cntmat    = (int*)take((size_t)NPB * NBUCK * 4);   // becomes offmat in-place
  int* total     = (int*)take((size_t)(NBUCK + 2) * 4);
  int* bptr      = (int*)take((size_t)(NBUCK + 2) * 4);
  float* part_a  = (float*)take(VB * 4);
  float* part_b  = (float*)take(VB * 4);
  float* scal    = (float*)take(64 * 4);

  // bucket staging buffer aliases x+rv (25.6MB); only live before k_gemm
  uint2* bstage = (uint2*)x;

  // partition-based CSR build
  hipMemsetAsync(total, 0, (size_t)(NBUCK + 2) * 4, stream);
  k_pcount<<<NPB, 256, 0, stream>>>(row, cntmat, total);
  k_bscan2<<<1, 1024, 0, stream>>>(total, bptr);
  k_colscan<<<NBUCK, 1024, 0, stream>>>(cntmat, bptr);
  k_ppart<<<NPB, 256, 0, stream>>>(row, col, data, cntmat, bstage);
  k_bbuild<<<NBUCK, 256, 0, stream>>>(bptr, bstage, rowptr, csr);

  // init: b_vec, x0=0, r0=p0=b_vec, gamma0=<b,b>  (overwrites bstage region)
  k_gemm<<<GEMM_B, 256, 0, stream>>>(feat, W, bias, x, rv, pv, part_a);
  k_init_scal<<<1, 256, 0, stream>>>(part_a, e0, scal);

  // 16 unrolled, device-guarded CG iterations
  for (int k = 0; k < MAXIT; ++k) {
    k_spmv<<<VB, VT, 0, stream>>>(scal, k, rowptr, csr, pv, ap, part_a);
    k_xr  <<<VB, VT, 0, stream>>>(scal, k, part_a, pv, ap, x, rv, part_b);
    k_pupd<<<VB, VT, 0, stream>>>(scal, k, part_b, rv, pv);
  }

  k_out<<<(NIDS * NCLS + 255) / 256, 256, 0, stream>>>(x, ids, out);
}

// Round 5
// 551.408 us; speedup vs baseline: 1.6564x; 1.0695x over previous
//
#include <hip/hip_runtime.h>
#include <math.h>

// Problem constants (from reference)
#define NNODE  100000
#define NEDGE  3200000
#define DFEAT  256
#define NCLS   40
#define NC_TOT 4000000        // NNODE * NCLS
#define NIDS   1000
#define TOLSQ  1.0e-4f        // TOL^2, TOL = 0.01
#define MAXIT  16

#define SB 2048               // spmv blocks (contiguous chunks, XCD-swizzled)
#define CPB 1954              // elements per spmv chunk: ceil(NC_TOT/SB)
#define XB 1024               // blocks for streaming float4 kernels
#define VT 256
#define GR     128            // rows per gemm block (2 rows/thread, 4 cslots)
#define GKC    32             // gemm K tile
#define GEMM_B 782            // ceil(NNODE / GR)

// Bucketed CSR build
#define RB      128           // rows per bucket (row >> 7)
#define NBUCK   782           // ceil(NNODE / RB)
#define BCAP    6144          // LDS edge capacity per bucket in k_bbuild
// Partition (counting sort) parameters
#define NPB     800           // partition blocks
#define EPB     4000          // edges per partition block (NPB*EPB == NEDGE)

__device__ __forceinline__ float block_reduce_256(float v, float* red) {
  int tid = threadIdx.x;
  red[tid] = v;
  __syncthreads();
  #pragma unroll
  for (int off = 128; off > 0; off >>= 1) {
    if (tid < off) red[tid] += red[tid + off];
    __syncthreads();
  }
  float res = red[0];
  __syncthreads();
  return res;
}

// ------------------- partition-based CSR build -------------------
__global__ void __launch_bounds__(256) k_pcount(const int* __restrict__ row,
                                                int* __restrict__ cntmat,
                                                int* __restrict__ total) {
  __shared__ int h[NBUCK];
  int tid = threadIdx.x, blk = blockIdx.x;
  for (int i = tid; i < NBUCK; i += 256) h[i] = 0;
  __syncthreads();
  int e0 = blk * EPB;
  for (int i = tid; i < EPB; i += 256) atomicAdd(&h[row[e0 + i] >> 7], 1);
  __syncthreads();
  for (int i = tid; i < NBUCK; i += 256) {
    int v = h[i];
    cntmat[blk * NBUCK + i] = v;
    if (v) atomicAdd(&total[i], v);
  }
}

__global__ void k_bscan2(const int* __restrict__ total, int* __restrict__ bptr) {
  __shared__ int s[1024];
  int tid = threadIdx.x;
  int v = (tid < NBUCK) ? total[tid] : 0;
  s[tid] = v;
  __syncthreads();
  for (int off = 1; off < 1024; off <<= 1) {
    int t = (tid >= off) ? s[tid - off] : 0;
    __syncthreads();
    s[tid] += t;
    __syncthreads();
  }
  if (tid < NBUCK) bptr[tid] = s[tid] - v;
  if (tid == 0) bptr[NBUCK] = NEDGE;
}

__global__ void __launch_bounds__(1024) k_colscan(int* __restrict__ cntmat,
                                                  const int* __restrict__ bptr) {
  __shared__ int s[1024];
  int b = blockIdx.x;
  int tid = threadIdx.x;
  int v = (tid < NPB) ? cntmat[tid * NBUCK + b] : 0;
  s[tid] = v;
  __syncthreads();
  for (int off = 1; off < 1024; off <<= 1) {
    int t = (tid >= off) ? s[tid - off] : 0;
    __syncthreads();
    s[tid] += t;
    __syncthreads();
  }
  if (tid < NPB) cntmat[tid * NBUCK + b] = bptr[b] + s[tid] - v;
}

__global__ void __launch_bounds__(256) k_ppart(const int* __restrict__ row,
    const int* __restrict__ col, const float* __restrict__ data,
    const int* __restrict__ offmat, uint2* __restrict__ bstage) {
  __shared__ int cnt[NBUCK];
  __shared__ int segs[NBUCK + 1];
  __shared__ int cur[NBUCK];
  __shared__ int goff[NBUCK];
  __shared__ int scp[256];
  __shared__ unsigned short bof[EPB];
  __shared__ uint2 pay[EPB];
  int tid = threadIdx.x, blk = blockIdx.x;
  int e0 = blk * EPB;

  for (int i = tid; i < NBUCK; i += 256) {
    cnt[i] = 0;
    goff[i] = offmat[blk * NBUCK + i];
  }
  __syncthreads();
  for (int i = tid; i < EPB; i += 256) atomicAdd(&cnt[row[e0 + i] >> 7], 1);
  __syncthreads();

  int t4 = tid * 4;
  int l0 = (t4 + 0 < NBUCK) ? cnt[t4 + 0] : 0;
  int l1 = (t4 + 1 < NBUCK) ? cnt[t4 + 1] : 0;
  int l2 = (t4 + 2 < NBUCK) ? cnt[t4 + 2] : 0;
  int l3 = (t4 + 3 < NBUCK) ? cnt[t4 + 3] : 0;
  int mysum = l0 + l1 + l2 + l3;
  scp[tid] = mysum;
  __syncthreads();
  for (int off = 1; off < 256; off <<= 1) {
    int t = (tid >= off) ? scp[tid - off] : 0;
    __syncthreads();
    scp[tid] += t;
    __syncthreads();
  }
  int base = scp[tid] - mysum;
  if (t4 + 0 <= NBUCK) segs[t4 + 0] = base;  base += l0;
  if (t4 + 1 <= NBUCK) segs[t4 + 1] = base;  base += l1;
  if (t4 + 2 <= NBUCK) segs[t4 + 2] = base;  base += l2;
  if (t4 + 3 <= NBUCK) segs[t4 + 3] = base;
  for (int i = tid; i < NBUCK; i += 256) cur[i] = 0;
  __syncthreads();

  for (int b = tid; b < NBUCK; b += 256) {
    int s1 = segs[b + 1];
    for (int i = segs[b]; i < s1; ++i) bof[i] = (unsigned short)b;
  }
  for (int i = tid; i < EPB; i += 256) {
    int rr = row[e0 + i];
    int b = rr >> 7;
    int rk = atomicAdd(&cur[b], 1);
    pay[segs[b] + rk] = make_uint2(((unsigned)(rr & (RB - 1)) << 17) | (unsigned)col[e0 + i],
                                   __float_as_uint(data[e0 + i]));
  }
  __syncthreads();
  for (int i = tid; i < EPB; i += 256) {
    int b = bof[i];
    bstage[goff[b] + (i - segs[b])] = pay[i];
  }
}

__global__ void __launch_bounds__(256) k_bbuild(const int* __restrict__ bptr,
    const uint2* __restrict__ bstage, int* __restrict__ rowptr,
    int2* __restrict__ csr) {
  __shared__ uint2 ebuf[BCAP];
  __shared__ int deg[RB];
  __shared__ int sc[RB];
  __shared__ int cur[RB];
  int b = blockIdx.x;
  int s0 = bptr[b], s1 = bptr[b + 1];
  int n = s1 - s0;
  if (n > BCAP) n = BCAP;
  int tid = threadIdx.x;
  if (tid < RB) deg[tid] = 0;
  __syncthreads();
  for (int i = tid; i < n; i += 256) {
    uint2 e = bstage[s0 + i];
    ebuf[i] = e;
    atomicAdd(&deg[e.x >> 17], 1);
  }
  __syncthreads();
  if (tid < RB) sc[tid] = deg[tid];
  __syncthreads();
  for (int off = 1; off < RB; off <<= 1) {
    int t = 0;
    if (tid >= off && tid < RB) t = sc[tid - off];
    __syncthreads();
    if (tid < RB) sc[tid] += t;
    __syncthreads();
  }
  if (tid < RB) {
    int ex = sc[tid] - deg[tid];
    cur[tid] = ex;
    int grow = b * RB + tid;
    if (grow < NNODE) rowptr[grow] = s0 + ex;
  }
  if (b == 0 && tid == 0) rowptr[NNODE] = NEDGE;
  __syncthreads();
  for (int i = tid; i < n; i += 256) {
    uint2 e = ebuf[i];
    int lr = e.x >> 17;
    int pos = atomicAdd(&cur[lr], 1);
    csr[s0 + pos] = make_int2((int)(e.x & 0x1FFFF), (int)e.y);
  }
}

// ------------------- init: b_vec = X@W + b; x=0; r=p=b_vec; <b,b> partials ---
__global__ void __launch_bounds__(256) k_gemm(const float* __restrict__ feat,
    const float* __restrict__ W, const float* __restrict__ bias,
    float* __restrict__ x, float* __restrict__ r, float* __restrict__ p,
    float* __restrict__ part) {
  __shared__ float ftile[GR][GKC + 1];
  __shared__ float wtile[GKC * NCLS];
  __shared__ float red[256];
  int tid = threadIdx.x;
  int r0 = blockIdx.x * GR;
  int rl0 = (tid >> 2) * 2;
  int cbase = (tid & 3) * 10;
  float acc0[10], acc1[10];
  #pragma unroll
  for (int j = 0; j < 10; ++j) {
    float bv = bias[cbase + j];
    acc0[j] = bv;
    acc1[j] = bv;
  }

  for (int k0 = 0; k0 < DFEAT; k0 += GKC) {
    __syncthreads();
    #pragma unroll
    for (int it = 0; it < 4; ++it) {
      int i = tid + it * 256;
      int rr = i >> 3, kq = i & 7;
      int grow = r0 + rr;
      float4 v = make_float4(0.f, 0.f, 0.f, 0.f);
      if (grow < NNODE)
        v = *(const float4*)(feat + (size_t)grow * DFEAT + k0 + kq * 4);
      ftile[rr][kq * 4 + 0] = v.x;
      ftile[rr][kq * 4 + 1] = v.y;
      ftile[rr][kq * 4 + 2] = v.z;
      ftile[rr][kq * 4 + 3] = v.w;
    }
    #pragma unroll
    for (int it = 0; it < 5; ++it) {
      int i = tid + it * 256;
      wtile[i] = W[k0 * NCLS + i];
    }
    __syncthreads();
    #pragma unroll 4
    for (int kk = 0; kk < GKC; ++kk) {
      float f0 = ftile[rl0][kk];
      float f1 = ftile[rl0 + 1][kk];
      const float* wr = &wtile[kk * NCLS + cbase];
      #pragma unroll
      for (int j = 0; j < 10; ++j) {
        float w = wr[j];
        acc0[j] = fmaf(f0, w, acc0[j]);
        acc1[j] = fmaf(f1, w, acc1[j]);
      }
    }
  }

  float local = 0.f;
  int g0 = r0 + rl0, g1 = g0 + 1;
  if (g0 < NNODE) {
    size_t b0 = (size_t)g0 * NCLS + cbase;
    #pragma unroll
    for (int j = 0; j < 10; ++j) {
      float a = acc0[j];
      r[b0 + j] = a; p[b0 + j] = a; x[b0 + j] = 0.f;
      local = fmaf(a, a, local);
    }
  }
  if (g1 < NNODE) {
    size_t b1 = (size_t)g1 * NCLS + cbase;
    #pragma unroll
    for (int j = 0; j < 10; ++j) {
      float a = acc1[j];
      r[b1 + j] = a; p[b1 + j] = a; x[b1 + j] = 0.f;
      local = fmaf(a, a, local);
    }
  }
  float tot = block_reduce_256(local, red);
  if (tid == 0) part[blockIdx.x] = tot;
}

// scalars: scal[0]=omega(=1-eps), scal[1]=atol2, scal[2+k]=gamma_k
__global__ void k_init_scal(const float* __restrict__ part, const float* __restrict__ e0,
                            float* __restrict__ scal) {
  __shared__ float red[256];
  float local = 0.f;
  for (int i = threadIdx.x; i < GEMM_B; i += 256) local += part[i];
  float bs = block_reduce_256(local, red);
  if (threadIdx.x == 0) {
    float eps = 1.f / (1.f + expf(-e0[0]));
    scal[0] = 1.f - eps;
    scal[1] = TOLSQ * bs;
    scal[2] = bs;          // gamma_0 = <r0,r0> = <b,b>
  }
}

// ------------------- CG iteration kernels (device-side convergence guard) ---
// Contiguous chunk per block + bijective XCD swizzle: each XCD owns a
// contiguous 1/8 of rows -> its CSR slice (3.2MB) is L2-resident.
__global__ void __launch_bounds__(VT) k_spmv(const float* __restrict__ scal, int k,
    const int* __restrict__ rowptr, const int2* __restrict__ csr,
    const float* __restrict__ p, float* __restrict__ Ap, float* __restrict__ part) {
  float gamma = scal[2 + k], atol2 = scal[1];
  if (!(gamma > atol2)) return;               // mirrors JAX while cond (rs > atol2)
  float omega = scal[0];
  int b = blockIdx.x;
  int chunk = (b & 7) * (SB / 8) + (b >> 3);  // bijective: 2048 = 8 * 256
  int ebase = chunk * CPB;
  float local = 0.f;
  #pragma unroll
  for (int it = 0; it < 8; ++it) {            // 8*256 = 2048 >= CPB
    int e = ebase + threadIdx.x + it * VT;
    if (it * VT + threadIdx.x < CPB && e < NC_TOT) {
      int rr = e / NCLS;
      int c = e - rr * NCLS;
      int s0 = rowptr[rr], s1 = rowptr[rr + 1];
      float acc = 0.f;
      #pragma unroll 8
      for (int j = s0; j < s1; ++j) {
        int2 pr = csr[j];
        acc = fmaf(__int_as_float(pr.y), p[pr.x * NCLS + c], acc);
      }
      float pe = p[e];
      float v = fmaf(-omega, acc, pe);        // f(p) = p - (1-eps) * A p
      Ap[e] = v;
      local = fmaf(pe, v, local);             // <p, Ap> partial
    }
  }
  __shared__ float red[256];
  float tot = block_reduce_256(local, red);
  if (threadIdx.x == 0) part[blockIdx.x] = tot;
}

__global__ void __launch_bounds__(VT) k_xr(const float* __restrict__ scal, int k,
    const float* __restrict__ part_in,
    const float* __restrict__ p, const float* __restrict__ Ap,
    float* __restrict__ x, float* __restrict__ r, float* __restrict__ part_out) {
  float gamma = scal[2 + k], atol2 = scal[1];
  if (!(gamma > atol2)) return;
  __shared__ float red[256];
  float lp = 0.f;
  for (int i = threadIdx.x; i < SB; i += VT) lp += part_in[i];
  float pap = block_reduce_256(lp, red);      // identical in every block
  float alpha = gamma / pap;
  const float4* p4 = (const float4*)p;
  const float4* a4 = (const float4*)Ap;
  float4* x4 = (float4*)x;
  float4* r4 = (float4*)r;
  float local = 0.f;
  int stride = gridDim.x * blockDim.x;
  for (int e = blockIdx.x * blockDim.x + threadIdx.x; e < NC_TOT / 4; e += stride) {
    float4 pe = p4[e], ae = a4[e], xe = x4[e], re = r4[e];
    xe.x = fmaf(alpha, pe.x, xe.x); xe.y = fmaf(alpha, pe.y, xe.y);
    xe.z = fmaf(alpha, pe.z, xe.z); xe.w = fmaf(alpha, pe.w, xe.w);
    re.x = fmaf(-alpha, ae.x, re.x); re.y = fmaf(-alpha, ae.y, re.y);
    re.z = fmaf(-alpha, ae.z, re.z); re.w = fmaf(-alpha, ae.w, re.w);
    x4[e] = xe; r4[e] = re;
    local = fmaf(re.x, re.x, local); local = fmaf(re.y, re.y, local);
    local = fmaf(re.z, re.z, local); local = fmaf(re.w, re.w, local);
  }
  float tot = block_reduce_256(local, red);
  if (threadIdx.x == 0) part_out[blockIdx.x] = tot;
}

__global__ void __launch_bounds__(VT) k_pupd(float* __restrict__ scal, int k,
    const float* __restrict__ part_in,
    const float* __restrict__ r, float* __restrict__ p) {
  float gamma = scal[2 + k], atol2 = scal[1];
  if (!(gamma > atol2)) {
    if (blockIdx.x == 0 && threadIdx.x == 0) scal[2 + k + 1] = gamma;  // propagate
    return;
  }
  __shared__ float red[256];
  float lp = 0.f;
  for (int i = threadIdx.x; i < XB; i += VT) lp += part_in[i];
  float gnew = block_reduce_256(lp, red);
  float beta = gnew / gamma;
  const float4* r4 = (const float4*)r;
  float4* p4 = (float4*)p;
  int stride = gridDim.x * blockDim.x;
  for (int e = blockIdx.x * blockDim.x + threadIdx.x; e < NC_TOT / 4; e += stride) {
    float4 pe = p4[e], re = r4[e];
    pe.x = fmaf(beta, pe.x, re.x); pe.y = fmaf(beta, pe.y, re.y);
    pe.z = fmaf(beta, pe.z, re.z); pe.w = fmaf(beta, pe.w, re.w);
    p4[e] = pe;
  }
  if (blockIdx.x == 0 && threadIdx.x == 0) scal[2 + k + 1] = gnew;
}

__global__ void k_out(const float* __restrict__ x, const int* __restrict__ ids,
                      float* __restrict__ out) {
  int j = blockIdx.x * blockDim.x + threadIdx.x;
  if (j < NIDS * NCLS) {
    int i = j / NCLS, c = j - (j / NCLS) * NCLS;
    out[j] = x[(size_t)ids[i] * NCLS + c];
  }
}

// ------------------- host launch -------------------
extern "C" void kernel_launch(void* const* d_in, const int* in_sizes, int n_in,
                              void* d_out, int out_size, void* d_ws, size_t ws_size,
                              hipStream_t stream) {
  const float* feat = (const float*)d_in[0];
  const float* W    = (const float*)d_in[1];
  const float* bias = (const float*)d_in[2];
  const float* e0   = (const float*)d_in[3];
  const float* data = (const float*)d_in[4];
  const int*   row  = (const int*)d_in[5];
  const int*   col  = (const int*)d_in[6];
  const int*   ids  = (const int*)d_in[7];
  float* out = (float*)d_out;

  size_t off = 0;
  char* base = (char*)d_ws;
  auto take = [&](size_t nbytes) -> void* {
    void* ptr = base + off;
    off += (nbytes + 255) & ~(size_t)255;
    return ptr;
  };
  float* x   = (float*)take((size_t)NC_TOT * 4);
  float* rv  = (float*)take((size_t)NC_TOT * 4);
  float* pv  = (float*)take((size_t)NC_TOT * 4);
  float* ap  = (float*)take((size_t)NC_TOT * 4);
  int2*  csr = (int2*)take((size_t)NEDGE * 8);
  int* rowptr    = (int*)take((size_t)(NNODE + 1) * 4);
  int* cntmat    = (int*)take((size_t)NPB * NBUCK * 4);   // becomes offmat in-place
  int* total     = (int*)take((size_t)(NBUCK + 2) * 4);
  int* bptr      = (int*)take((size_t)(NBUCK + 2) * 4);
  float* part_a  = (float*)take(SB * 4);
  float* part_b  = (float*)take(XB * 4);
  float* scal    = (float*)take(64 * 4);

  // bucket staging buffer aliases x+rv (25.6MB); only live before k_gemm
  uint2* bstage = (uint2*)x;

  // partition-based CSR build
  hipMemsetAsync(total, 0, (size_t)(NBUCK + 2) * 4, stream);
  k_pcount<<<NPB, 256, 0, stream>>>(row, cntmat, total);
  k_bscan2<<<1, 1024, 0, stream>>>(total, bptr);
  k_colscan<<<NBUCK, 1024, 0, stream>>>(cntmat, bptr);
  k_ppart<<<NPB, 256, 0, stream>>>(row, col, data, cntmat, bstage);
  k_bbuild<<<NBUCK, 256, 0, stream>>>(bptr, bstage, rowptr, csr);

  // init: b_vec, x0=0, r0=p0=b_vec, gamma0=<b,b>  (overwrites bstage region)
  k_gemm<<<GEMM_B, 256, 0, stream>>>(feat, W, bias, x, rv, pv, part_a);
  k_init_scal<<<1, 256, 0, stream>>>(part_a, e0, scal);

  // 16 unrolled, device-guarded CG iterations
  for (int k = 0; k < MAXIT; ++k) {
    k_spmv<<<SB, VT, 0, stream>>>(scal, k, rowptr, csr, pv, ap, part_a);
    k_xr  <<<XB, VT, 0, stream>>>(scal, k, part_a, pv, ap, x, rv, part_b);
    k_pupd<<<XB, VT, 0, stream>>>(scal, k, part_b, rv, pv);
  }

  k_out<<<(NIDS * NCLS + 255) / 256, 256, 0, stream>>>(x, ids, out);
}